// Round 1
// baseline (1276.490 us; speedup 1.0000x reference)
//
#include <hip/hip_runtime.h>
#include <stdint.h>

#define B_TOTAL 262144
#define TB 64
#define SLOT 16384          // bytes per stream activation slot: 64 rows * 128 cols * 2B
#define BUF1 81920          // second ping-pong bank offset (5 slots)
#define LDS_BYTES 163840    // 160 KiB
#define HEAD_W 204800       // bf16 weight elements per head in d_ws

typedef short v8s __attribute__((ext_vector_type(8)));
typedef float v4f __attribute__((ext_vector_type(4)));

union Frag { uint4 q; uint32_t d[4]; v8s v; };

__device__ __forceinline__ uint32_t relu2(uint32_t w) {
    // zero each bf16 half whose sign bit is set
    uint32_t m = ((w >> 15) & 0x00010001u) * 0xFFFFu;
    return w & ~m;
}
__device__ __forceinline__ unsigned short f2bf(float f) {
    uint32_t u = __float_as_uint(f);               // RNE f32 -> bf16 (finite inputs)
    return (unsigned short)((u + 0x7FFFu + ((u >> 16) & 1u)) >> 16);
}
__device__ __forceinline__ float bflo(uint32_t w) { return __uint_as_float(w << 16); }
__device__ __forceinline__ float bfhi(uint32_t w) { return __uint_as_float(w & 0xFFFF0000u); }

// LDS activation element [row][k] (bf16) lives at row*256 + ((k>>3) ^ (row&15))*16 + (k&7)*2

struct KParams {
    const float* x; const float* u; const float* mix; const float* P;
    const float* mb[6];     // main biases b1,b2,b3,b5,b6,b7   (head*3+L)
    const float* tb[6];     // teacher biases tb1..tb3, tb5..tb7
    const float* Wout[2];   // W4, W8 (fp32)
    const float* bout[2];   // b4, b8
    const unsigned short* wbf;  // bf16 weights in workspace
    float* out;
};

struct PrepParams { const float* src[12]; unsigned short* dst; };

__global__ __launch_bounds__(256) void prep_kernel(PrepParams pp) {
    const int ends[12] = {16384,81920,98304,163840,172032,204800,
                          221184,286720,303104,368640,376832,409600};
    int gi = (blockIdx.x * 256 + threadIdx.x) * 4;
    if (gi >= 409600) return;
    int s = 0;
    #pragma unroll
    for (int i = 0; i < 12; ++i) { if (gi >= ends[i]) s = i + 1; }
    int base = (s == 0) ? 0 : ends[s - 1];
    const float4 f = *(const float4*)(pp.src[s] + (gi - base));
    uint32_t lo = (uint32_t)f2bf(f.x) | ((uint32_t)f2bf(f.y) << 16);
    uint32_t hi = (uint32_t)f2bf(f.z) | ((uint32_t)f2bf(f.w) << 16);
    *(uint2*)(pp.dst + gi) = make_uint2(lo, hi);
}

template<bool SHARED_IN, bool TRELU, int N>
__device__ __forceinline__ void do_layer(char* lds, int inOff, int outOff,
                                         const unsigned short* W, const float* tb,
                                         int lane, int wave)
{
    const int l15 = lane & 15;
    const int l4  = lane >> 4;
    const int NCG = N >> 5;           // 32-col groups
    const int ntasks = 5 * NCG;
    for (int t = wave; t < ntasks; t += 4) {
        const int s  = t % 5;
        const int cg = t / 5;
        const char* inB = lds + inOff + (SHARED_IN ? 0 : s * SLOT);
        const unsigned short* Ws = W + s * (N * 128);
        const bool doRelu = TRELU && (s != 0);
        v4f acc[4][2];
        #pragma unroll
        for (int rt = 0; rt < 4; ++rt) {
            #pragma unroll
            for (int ct = 0; ct < 2; ++ct) acc[rt][ct] = (v4f){0.f, 0.f, 0.f, 0.f};
        }
        #pragma unroll
        for (int ks = 0; ks < 4; ++ks) {
            Frag aF[4];
            #pragma unroll
            for (int rt = 0; rt < 4; ++rt) {
                const int row = rt * 16 + l15;
                const int gg  = ks * 4 + l4;
                aF[rt].q = *(const uint4*)(inB + row * 256 + ((gg ^ (row & 15)) << 4));
                if (doRelu) {
                    #pragma unroll
                    for (int j = 0; j < 4; ++j) aF[rt].d[j] = relu2(aF[rt].d[j]);
                }
            }
            Frag bF[2];
            #pragma unroll
            for (int ct = 0; ct < 2; ++ct) {
                const int o = cg * 32 + ct * 16 + l15;
                bF[ct].q = *(const uint4*)(Ws + o * 128 + ks * 32 + l4 * 8);
            }
            #pragma unroll
            for (int rt = 0; rt < 4; ++rt) {
                #pragma unroll
                for (int ct = 0; ct < 2; ++ct)
                    acc[rt][ct] = __builtin_amdgcn_mfma_f32_16x16x32_bf16(
                        aF[rt].v, bF[ct].v, acc[rt][ct], 0, 0, 0);
            }
        }
        float bias0 = 0.f, bias1 = 0.f;
        if (s != 0) {
            bias0 = tb[(s - 1) * N + cg * 32 + l15];
            bias1 = tb[(s - 1) * N + cg * 32 + 16 + l15];
        }
        char* outB = lds + outOff + s * SLOT;
        #pragma unroll
        for (int rt = 0; rt < 4; ++rt) {
            #pragma unroll
            for (int ct = 0; ct < 2; ++ct) {
                const int o = cg * 32 + ct * 16 + l15;
                const float bs = ct ? bias1 : bias0;
                #pragma unroll
                for (int r = 0; r < 4; ++r) {
                    const int row = rt * 16 + l4 * 4 + r;   // C layout: row=(lane>>4)*4+reg
                    *(unsigned short*)(outB + row * 256 + (((o >> 3) ^ (row & 15)) << 4)
                                        + ((o & 7) << 1)) = f2bf(acc[rt][ct][r] + bs);
                }
            }
        }
    }
}

template<int N>
__device__ __forceinline__ void do_combine(char* lds, int bufOff, const float* mbias,
                                           float c0, const float* cP, int tid)
{
    const int NG = N >> 3;
    const int SH = (N == 128) ? 4 : 3;
    const int total = TB * NG;
    for (int G = tid; G < total; G += 256) {
        const int row = G >> SH;
        const int gg  = G & (NG - 1);
        const int ab = row * 256 + ((gg ^ (row & 15)) << 4);
        uint32_t wv[5][4];
        #pragma unroll
        for (int s = 0; s < 5; ++s) {
            uint4 q = *(const uint4*)(lds + bufOff + s * SLOT + ab);
            wv[s][0] = q.x; wv[s][1] = q.y; wv[s][2] = q.z; wv[s][3] = q.w;
        }
        const float4 ba = *(const float4*)(mbias + gg * 8);
        const float4 bb = *(const float4*)(mbias + gg * 8 + 4);
        const float bsv[8] = {ba.x, ba.y, ba.z, ba.w, bb.x, bb.y, bb.z, bb.w};
        uint32_t dout[4];
        #pragma unroll
        for (int j = 0; j < 4; ++j) {
            float lo = c0 * (bflo(wv[0][j]) + bsv[2 * j]);
            float hi = c0 * (bfhi(wv[0][j]) + bsv[2 * j + 1]);
            #pragma unroll
            for (int s = 1; s < 5; ++s) {
                lo = fmaf(cP[s - 1], bflo(wv[s][j]), lo);
                hi = fmaf(cP[s - 1], bfhi(wv[s][j]), hi);
            }
            lo = fmaxf(lo, 0.f); hi = fmaxf(hi, 0.f);
            dout[j] = (uint32_t)f2bf(lo) | ((uint32_t)f2bf(hi) << 16);
        }
        *(uint4*)(lds + bufOff + ab) = make_uint4(dout[0], dout[1], dout[2], dout[3]);
    }
}

extern "C" __global__ __launch_bounds__(256, 1)
void critic_kernel(KParams p)
{
    extern __shared__ char lds[];
    const int tid  = threadIdx.x;
    const int lane = tid & 63;
    const int wave = tid >> 6;
    const int rowBase = blockIdx.x * TB;

    const float m  = p.mix[0];
    const float c0 = 1.f - m;
    float cP[4];
    #pragma unroll
    for (int k = 0; k < 4; ++k) cP[k] = m * p.P[k];

    #pragma unroll 1
    for (int head = 0; head < 2; ++head) {
        // ---- stage xu = [x|u] (fp32 HBM/L2) -> bf16 swizzled LDS, BUF0 slot 0 ----
        for (int G = tid; G < 1024; G += 256) {
            const int row = G >> 4;
            const int gg  = G & 15;
            const int grow = rowBase + row;
            float4 fa, fb;
            if (gg < 12) {
                const float* s2 = p.x + grow * 96 + gg * 8;
                fa = *(const float4*)s2; fb = *(const float4*)(s2 + 4);
            } else {
                const float* s2 = p.u + grow * 32 + (gg - 12) * 8;
                fa = *(const float4*)s2; fb = *(const float4*)(s2 + 4);
            }
            uint32_t d0 = (uint32_t)f2bf(fa.x) | ((uint32_t)f2bf(fa.y) << 16);
            uint32_t d1 = (uint32_t)f2bf(fa.z) | ((uint32_t)f2bf(fa.w) << 16);
            uint32_t d2 = (uint32_t)f2bf(fb.x) | ((uint32_t)f2bf(fb.y) << 16);
            uint32_t d3 = (uint32_t)f2bf(fb.z) | ((uint32_t)f2bf(fb.w) << 16);
            *(uint4*)(lds + row * 256 + ((gg ^ (row & 15)) << 4)) = make_uint4(d0, d1, d2, d3);
        }
        __syncthreads();

        const unsigned short* wb = p.wbf + head * HEAD_W;
        const int hb = head * 3;

        // L1: xu(shared) -> BUF1 (teachers: pre+bias; main: raw lin)
        do_layer<true,  false, 128>(lds, 0,    BUF1, wb,           p.tb[hb + 0], lane, wave);
        __syncthreads();
        do_combine<128>(lds, BUF1, p.mb[hb + 0], c0, cP, tid);
        __syncthreads();
        // L2: BUF1 -> BUF0 (teacher A-frags relu'd on read)
        do_layer<false, true,  128>(lds, BUF1, 0,    wb + 81920,   p.tb[hb + 1], lane, wave);
        __syncthreads();
        do_combine<128>(lds, 0,    p.mb[hb + 1], c0, cP, tid);
        __syncthreads();
        // L3: BUF0 -> BUF1, out = 64
        do_layer<false, true,  64 >(lds, 0,    BUF1, wb + 163840,  p.tb[hb + 2], lane, wave);
        __syncthreads();
        do_combine<64 >(lds, BUF1, p.mb[hb + 2], c0, cP, tid);
        __syncthreads();

        // L4: per-row fp32 dot of h3[64] with W4/W8 (fp32), + bias
        if (tid < 64) {
            const int row = tid;
            const char* hB = lds + BUF1;   // slot 0 = relu'd main h3
            const float* Wo = p.Wout[head];
            float dot = p.bout[head][0];
            #pragma unroll
            for (int g = 0; g < 8; ++g) {
                uint4 q = *(const uint4*)(hB + row * 256 + ((g ^ (row & 15)) << 4));
                const float4 w0 = *(const float4*)(Wo + g * 8);
                const float4 w1 = *(const float4*)(Wo + g * 8 + 4);
                dot = fmaf(bflo(q.x), w0.x, dot); dot = fmaf(bfhi(q.x), w0.y, dot);
                dot = fmaf(bflo(q.y), w0.z, dot); dot = fmaf(bfhi(q.y), w0.w, dot);
                dot = fmaf(bflo(q.z), w1.x, dot); dot = fmaf(bfhi(q.z), w1.y, dot);
                dot = fmaf(bflo(q.w), w1.z, dot); dot = fmaf(bfhi(q.w), w1.w, dot);
            }
            p.out[head * B_TOTAL + rowBase + row] = dot;
        }
        __syncthreads();
    }
}

extern "C" void kernel_launch(void* const* d_in, const int* in_sizes, int n_in,
                              void* d_out, int out_size, void* d_ws, size_t ws_size,
                              hipStream_t stream)
{
    (void)in_sizes; (void)n_in; (void)out_size; (void)ws_size;

    PrepParams pp;
    const int sidx[12] = {4, 20, 6, 22, 8, 24, 12, 26, 14, 28, 16, 30};
    for (int i = 0; i < 12; ++i) pp.src[i] = (const float*)d_in[sidx[i]];
    pp.dst = (unsigned short*)d_ws;

    KParams kp;
    kp.x = (const float*)d_in[0];  kp.u = (const float*)d_in[1];
    kp.mix = (const float*)d_in[2]; kp.P = (const float*)d_in[3];
    const int mbi[6] = {5, 7, 9, 13, 15, 17};
    const int tbi[6] = {21, 23, 25, 27, 29, 31};
    for (int i = 0; i < 6; ++i) {
        kp.mb[i] = (const float*)d_in[mbi[i]];
        kp.tb[i] = (const float*)d_in[tbi[i]];
    }
    kp.Wout[0] = (const float*)d_in[10]; kp.Wout[1] = (const float*)d_in[18];
    kp.bout[0] = (const float*)d_in[11]; kp.bout[1] = (const float*)d_in[19];
    kp.wbf = (const unsigned short*)d_ws;
    kp.out = (float*)d_out;

    // allow 160 KiB dynamic LDS (idempotent; safe under graph capture)
    (void)hipFuncSetAttribute((const void*)critic_kernel,
                              hipFuncAttributeMaxDynamicSharedMemorySize, LDS_BYTES);

    hipLaunchKernelGGL(prep_kernel, dim3(400), dim3(256), 0, stream, pp);
    hipLaunchKernelGGL(critic_kernel, dim3(4096), dim3(256), LDS_BYTES, stream, kp);
}

// Round 2
// 882.186 us; speedup vs baseline: 1.4470x; 1.4470x over previous
//
#include <hip/hip_runtime.h>
#include <hip/hip_bf16.h>
#include <stdint.h>

#define B_TOTAL 262144
#define TB 64
#define SLOT 16384          // 64 rows * 128 cols * 2B
#define BUF1 81920          // second bank: 5 slots
#define LDS_BYTES 163840    // 160 KiB
#define HEAD_W 204800       // bf16 weight elements per head in d_ws

typedef short v8s __attribute__((ext_vector_type(8)));
typedef float v4f __attribute__((ext_vector_type(4)));

union Frag { uint4 q; uint32_t d[4]; v8s v; };

__device__ __forceinline__ unsigned short f2bf(float f) {
    uint32_t u = __float_as_uint(f);
    return (unsigned short)((u + 0x7FFFu + ((u >> 16) & 1u)) >> 16);
}
__device__ __forceinline__ uint32_t pack2(float a, float b) {
    union { __hip_bfloat162 h; uint32_t u; } p;
    p.h = __float22bfloat162_rn(make_float2(a, b));
    return p.u;
}

// LDS element [row][k] (bf16) at row*256 + ((k>>3) ^ (row&15))*16 + (k&7)*2

struct KParams {
    const float* x; const float* u; const float* mix; const float* P;
    const float* mb[6];
    const float* tb[6];
    const float* Wout[2];
    const float* bout[2];
    const unsigned short* wbf;
    float* out;
};

struct PrepParams { const float* src[12]; unsigned short* dst; };

__global__ __launch_bounds__(256) void prep_kernel(PrepParams pp) {
    const int ends[12] = {16384,81920,98304,163840,172032,204800,
                          221184,286720,303104,368640,376832,409600};
    int gi = (blockIdx.x * 256 + threadIdx.x) * 4;
    if (gi >= 409600) return;
    int s = 0;
    #pragma unroll
    for (int i = 0; i < 12; ++i) { if (gi >= ends[i]) s = i + 1; }
    int base = (s == 0) ? 0 : ends[s - 1];
    const float4 f = *(const float4*)(pp.src[s] + (gi - base));
    *(uint2*)(pp.dst + gi) = make_uint2(pack2(f.x, f.y), pack2(f.z, f.w));
}

__device__ __forceinline__ void stage_xu(char* lds, const float* x, const float* u,
                                         int rowBase, int tid)
{
    for (int G = tid; G < 1024; G += 256) {
        const int row = G >> 4;
        const int gg  = G & 15;
        const int grow = rowBase + row;
        float4 fa, fb;
        if (gg < 12) {
            const float* s2 = x + grow * 96 + gg * 8;
            fa = *(const float4*)s2; fb = *(const float4*)(s2 + 4);
        } else {
            const float* s2 = u + grow * 32 + (gg - 12) * 8;
            fa = *(const float4*)s2; fb = *(const float4*)(s2 + 4);
        }
        *(uint4*)(lds + row * 256 + ((gg ^ (row & 15)) << 4)) =
            make_uint4(pack2(fa.x, fa.y), pack2(fa.z, fa.w),
                       pack2(fb.x, fb.y), pack2(fb.z, fb.w));
    }
}

// One fused layer: wave cg computes ALL 5 streams for its output-column group.
// MFMA operands swapped (W as A, X as B) so accumulator holds, per lane:
//   batch row b = bt*16 + (lane&15), output cols obase + (lane>>4)*4 + r (consecutive)
// -> combine (bias + mix + relu) entirely in registers, b64 LDS writes.
// N==64 is the final layer: no LDS writes; fused dot with Wout into pgrid.
template<bool SHARED_IN, int N>
__device__ __forceinline__ void layer_fwd(char* lds, int inOff, int outOff,
        const unsigned short* W, const float* mbias, const float* tbias,
        float c0, const float* cP, int lane, int wave,
        const float* Wout, float* pgrid)
{
    constexpr int OT = N / 64;          // 16-col output tiles per wave (2 or 1)
    constexpr bool FINAL = (N == 64);
    const int l15  = lane & 15;
    const int quad = lane >> 4;
    const int cg   = wave;

    v4f acc[5][OT][4];
    #pragma unroll
    for (int s = 0; s < 5; ++s)
        #pragma unroll
        for (int ot = 0; ot < OT; ++ot)
            #pragma unroll
            for (int bt = 0; bt < 4; ++bt)
                acc[s][ot][bt] = (v4f){0.f, 0.f, 0.f, 0.f};

    #pragma unroll
    for (int ks = 0; ks < 4; ++ks) {
        Frag xS[4];
        if constexpr (SHARED_IN) {
            #pragma unroll
            for (int bt = 0; bt < 4; ++bt) {
                const int row = bt * 16 + l15;
                const int gg  = ks * 4 + quad;
                xS[bt].q = *(const uint4*)(lds + inOff + row * 256 + ((gg ^ (row & 15)) << 4));
            }
        }
        #pragma unroll
        for (int s = 0; s < 5; ++s) {
            Frag xF[4];
            if constexpr (!SHARED_IN) {
                #pragma unroll
                for (int bt = 0; bt < 4; ++bt) {
                    const int row = bt * 16 + l15;
                    const int gg  = ks * 4 + quad;
                    xF[bt].q = *(const uint4*)(lds + inOff + s * SLOT + row * 256
                                               + ((gg ^ (row & 15)) << 4));
                }
            }
            Frag wF[OT];
            #pragma unroll
            for (int ot = 0; ot < OT; ++ot) {
                const int o = cg * (OT * 16) + ot * 16 + l15;
                wF[ot].q = *(const uint4*)(W + s * (N * 128) + o * 128 + ks * 32 + quad * 8);
            }
            #pragma unroll
            for (int ot = 0; ot < OT; ++ot)
                #pragma unroll
                for (int bt = 0; bt < 4; ++bt)
                    acc[s][ot][bt] = __builtin_amdgcn_mfma_f32_16x16x32_bf16(
                        wF[ot].v, (SHARED_IN ? xS[bt].v : xF[bt].v), acc[s][ot][bt], 0, 0, 0);
        }
    }

    if constexpr (!FINAL) {
        #pragma unroll
        for (int ot = 0; ot < OT; ++ot) {
            const int obase = cg * 32 + ot * 16 + quad * 4;
            const float4 mB = *(const float4*)(mbias + obase);
            float4 tB[4];
            #pragma unroll
            for (int s = 0; s < 4; ++s)
                tB[s] = *(const float4*)(tbias + s * N + obase);
            #pragma unroll
            for (int bt = 0; bt < 4; ++bt) {
                const int row = bt * 16 + l15;
                char* ab = lds + outOff + row * 256 + (((obase >> 3) ^ (row & 15)) << 4)
                           + ((obase & 7) << 1);
                float vr[4];
                vr[0] = c0 * (acc[0][ot][bt][0] + mB.x);
                vr[1] = c0 * (acc[0][ot][bt][1] + mB.y);
                vr[2] = c0 * (acc[0][ot][bt][2] + mB.z);
                vr[3] = c0 * (acc[0][ot][bt][3] + mB.w);
                uint2 tw[4];
                #pragma unroll
                for (int s = 0; s < 4; ++s) {
                    float t0 = acc[s + 1][ot][bt][0] + tB[s].x;
                    float t1 = acc[s + 1][ot][bt][1] + tB[s].y;
                    float t2 = acc[s + 1][ot][bt][2] + tB[s].z;
                    float t3 = acc[s + 1][ot][bt][3] + tB[s].w;
                    vr[0] = fmaf(cP[s], t0, vr[0]);
                    vr[1] = fmaf(cP[s], t1, vr[1]);
                    vr[2] = fmaf(cP[s], t2, vr[2]);
                    vr[3] = fmaf(cP[s], t3, vr[3]);
                    tw[s] = make_uint2(pack2(fmaxf(t0, 0.f), fmaxf(t1, 0.f)),
                                       pack2(fmaxf(t2, 0.f), fmaxf(t3, 0.f)));
                }
                *(uint2*)ab = make_uint2(pack2(fmaxf(vr[0], 0.f), fmaxf(vr[1], 0.f)),
                                         pack2(fmaxf(vr[2], 0.f), fmaxf(vr[3], 0.f)));
                #pragma unroll
                for (int s = 0; s < 4; ++s)
                    *(uint2*)(ab + (s + 1) * SLOT) = tw[s];
            }
        }
    } else {
        const int obase = cg * 16 + quad * 4;
        const float4 mB = *(const float4*)(mbias + obase);
        float4 tB[4];
        #pragma unroll
        for (int s = 0; s < 4; ++s)
            tB[s] = *(const float4*)(tbias + s * N + obase);
        const float4 wo = *(const float4*)(Wout + obase);
        float psum[4];
        #pragma unroll
        for (int bt = 0; bt < 4; ++bt) {
            float vr[4];
            vr[0] = c0 * (acc[0][0][bt][0] + mB.x);
            vr[1] = c0 * (acc[0][0][bt][1] + mB.y);
            vr[2] = c0 * (acc[0][0][bt][2] + mB.z);
            vr[3] = c0 * (acc[0][0][bt][3] + mB.w);
            #pragma unroll
            for (int s = 0; s < 4; ++s) {
                vr[0] = fmaf(cP[s], acc[s + 1][0][bt][0] + tB[s].x, vr[0]);
                vr[1] = fmaf(cP[s], acc[s + 1][0][bt][1] + tB[s].y, vr[1]);
                vr[2] = fmaf(cP[s], acc[s + 1][0][bt][2] + tB[s].z, vr[2]);
                vr[3] = fmaf(cP[s], acc[s + 1][0][bt][3] + tB[s].w, vr[3]);
            }
            float pp = fmaxf(vr[0], 0.f) * wo.x + fmaxf(vr[1], 0.f) * wo.y
                     + fmaxf(vr[2], 0.f) * wo.z + fmaxf(vr[3], 0.f) * wo.w;
            pp += __shfl_xor(pp, 16);
            pp += __shfl_xor(pp, 32);
            psum[bt] = pp;
        }
        if (lane < 16) {
            #pragma unroll
            for (int bt = 0; bt < 4; ++bt)
                pgrid[cg * 64 + bt * 16 + lane] = psum[bt];
        }
    }
}

extern "C" __global__ __launch_bounds__(256, 1)
void critic_kernel(KParams p)
{
    extern __shared__ char lds[];
    const int tid  = threadIdx.x;
    const int lane = tid & 63;
    const int wave = tid >> 6;
    const int rowBase = blockIdx.x * TB;

    const float m  = p.mix[0];
    const float c0 = 1.f - m;
    float cP[4];
    #pragma unroll
    for (int k = 0; k < 4; ++k) cP[k] = m * p.P[k];

    stage_xu(lds, p.x, p.u, rowBase, tid);

    #pragma unroll 1
    for (int head = 0; head < 2; ++head) {
        __syncthreads();
        const unsigned short* wb = p.wbf + head * HEAD_W;
        const int hb = head * 3;

        // L1: xu (BUF0.slot0, shared) -> BUF1 (5 relu'd streams)
        layer_fwd<true, 128>(lds, 0, BUF1, wb, p.mb[hb + 0], p.tb[hb + 0],
                             c0, cP, lane, wave, nullptr, nullptr);
        __syncthreads();
        // L2: BUF1 -> BUF0 (overwrites xu slot)
        layer_fwd<false, 128>(lds, BUF1, 0, wb + 81920, p.mb[hb + 1], p.tb[hb + 1],
                              c0, cP, lane, wave, nullptr, nullptr);
        __syncthreads();
        // L3 + L4: BUF0 -> register combine -> dot(Wout) -> pgrid (in BUF1)
        layer_fwd<false, 64>(lds, 0, 0, wb + 163840, p.mb[hb + 2], p.tb[hb + 2],
                             c0, cP, lane, wave, p.Wout[head], (float*)(lds + BUF1));
        __syncthreads();

        if (tid < 64) {
            const float* pg = (const float*)(lds + BUF1);
            p.out[head * B_TOTAL + rowBase + tid] =
                p.bout[head][0] + pg[tid] + pg[64 + tid] + pg[128 + tid] + pg[192 + tid];
        }
        if (head == 0)
            stage_xu(lds, p.x, p.u, rowBase, tid);   // L2 overwrote xu; restage for head 1
    }
}

extern "C" void kernel_launch(void* const* d_in, const int* in_sizes, int n_in,
                              void* d_out, int out_size, void* d_ws, size_t ws_size,
                              hipStream_t stream)
{
    (void)in_sizes; (void)n_in; (void)out_size; (void)ws_size;

    PrepParams pp;
    const int sidx[12] = {4, 20, 6, 22, 8, 24, 12, 26, 14, 28, 16, 30};
    for (int i = 0; i < 12; ++i) pp.src[i] = (const float*)d_in[sidx[i]];
    pp.dst = (unsigned short*)d_ws;

    KParams kp;
    kp.x = (const float*)d_in[0];  kp.u = (const float*)d_in[1];
    kp.mix = (const float*)d_in[2]; kp.P = (const float*)d_in[3];
    const int mbi[6] = {5, 7, 9, 13, 15, 17};
    const int tbi[6] = {21, 23, 25, 27, 29, 31};
    for (int i = 0; i < 6; ++i) {
        kp.mb[i] = (const float*)d_in[mbi[i]];
        kp.tb[i] = (const float*)d_in[tbi[i]];
    }
    kp.Wout[0] = (const float*)d_in[10]; kp.Wout[1] = (const float*)d_in[18];
    kp.bout[0] = (const float*)d_in[11]; kp.bout[1] = (const float*)d_in[19];
    kp.wbf = (const unsigned short*)d_ws;
    kp.out = (float*)d_out;

    (void)hipFuncSetAttribute((const void*)critic_kernel,
                              hipFuncAttributeMaxDynamicSharedMemorySize, LDS_BYTES);

    hipLaunchKernelGGL(prep_kernel, dim3(400), dim3(256), 0, stream, pp);
    hipLaunchKernelGGL(critic_kernel, dim3(4096), dim3(256), LDS_BYTES, stream, kp);
}